// Round 13
// baseline (24078.885 us; speedup 1.0000x reference)
//
#include <hip/hip_runtime.h>
#include <math.h>

#define BDIM 512
#define BR   32
#define D    128
#define SPD  130      // state LDS row stride (doubles)
#define TT   32
#define NB   8
#define NL   3

__device__ __forceinline__ double c19_act_d(double x) {
    const double PI_D = 3.14159265358979323846;
    const double L6   = 6.0 * PI_D;
    double scaled = x * (1.0 / PI_D);
    double n = floor(scaled);
    double t = scaled - n;
    double h = t * (1.0 - t);
    double halfn = n * 0.5;
    double fr = halfn - floor(halfn);   // 0.0 (even n) or 0.5 (odd n)
    double sgn = (fr < 0.25) ? 1.0 : -1.0;
    double core = PI_D * (sgn * h + 4.0 * h * h);
    double r = core;
    r = (x <= -L6) ? (x + L6) : r;
    r = (x >=  L6) ? (x - L6) : r;
    return r;
}

// Barrier-free t-loop: state rows are wave-private in EVERY phase
// (wave w owns rows 4w..4w+3); W is read per-lane from L2 (no LDS staging).
// LDS ~52 KB -> 2-3 blocks/CU (4-6 waves/SIMD) of independent waves.
__global__ __launch_bounds__(BDIM) void miniphi_kernel(
    const float* __restrict__ x,  const float* __restrict__ Wi, const float* __restrict__ bi,
    const float* __restrict__ Wo, const float* __restrict__ bo,
    const float* __restrict__ g_state, const float* __restrict__ b_state,
    const float* __restrict__ Ws, const float* __restrict__ bs,
    const float* __restrict__ gs, const float* __restrict__ betas,
    float* __restrict__ out)
{
    __shared__ double sStateD[BR][SPD];    // 33280 B; wave-private rows
    __shared__ float  sWi[NB][D];          //  4096 B
    __shared__ float  sWo[D][NB];          //  4096 B
    __shared__ float  sBi[D], sGst[D], sBst[D];   // 1536 B
    __shared__ double sGsD[NL][D];         //  3072 B  g (f64)
    __shared__ double sGW[NL][D];          //  3072 B  (g @ W)[c]
    __shared__ double sBWbs[NL][D];        //  3072 B  (beta @ W)[c] + bs[c]
    __shared__ float  sBo[NB];             //  total ~52.3 KB

    const int tid = threadIdx.x;

    for (int i = tid; i < NB * D; i += BDIM) sWi[i >> 7][i & 127] = Wi[i];
    for (int i = tid; i < D * NB; i += BDIM) sWo[i >> 3][i & 7] = Wo[i];
    for (int i = tid; i < D; i += BDIM) { sBi[i] = bi[i]; sGst[i] = g_state[i]; sBst[i] = b_state[i]; }
    for (int i = tid; i < NL * D; i += BDIM) sGsD[i >> 7][i & 127] = (double)gs[i];
    if (tid < NB) sBo[tid] = bo[tid];
    for (int i = tid; i < BR * D; i += BDIM) sStateD[i >> 7][i & 127] = 0.0;
    // LN-fold per-layer column vectors (f64)
    if (tid < NL * D) {
        int l = tid >> 7, c = tid & 127;
        const float* wl = Ws + (size_t)l * D * D;
        double gw = 0.0, bw = 0.0;
        for (int k = 0; k < D; ++k) {
            double w = (double)wl[k * D + c];
            gw = fma((double)gs[l * D + k], w, gw);
            bw = fma((double)betas[l * D + k], w, bw);
        }
        sGW[l][c] = gw;
        sBWbs[l][c] = bw + (double)bs[l * D + c];
    }
    __syncthreads();   // the ONLY barrier (init); t-loop is barrier-free

    const int rLN = tid >> 4;        // 0..31 : LN row (16 lanes/row; wave w -> rows 4w..4w+3)
    const int sL  = tid & 15;        // 0..15 : lane owns cols {sL + 16*j, j=0..7}
    const int wv  = tid >> 6;        // wave 0..7
    const int l   = tid & 63;        // GEMM cols {2l, 2l+1}
    const int c0  = 2 * l;
    const int r0  = wv * 4;          // GEMM rows r0..r0+3 (== this wave's LN rows)
    const size_t rowg = (size_t)blockIdx.x * BR;

    for (int t = 0; t < TT; ++t) {
        // ---------- step 1: state = 0.618*(LN(h)*g+b) + 0.382*(x_t @ Wi + bi) ----------
        {
            const float* xp = x + (rowg + (size_t)rLN) * (TT * NB) + (size_t)t * NB;
            float4 xa = *(const float4*)(xp);
            float4 xb = *(const float4*)(xp + 4);
            double xv[8] = {(double)xa.x, (double)xa.y, (double)xa.z, (double)xa.w,
                            (double)xb.x, (double)xb.y, (double)xb.z, (double)xb.w};

            double v[8];
            #pragma unroll
            for (int j = 0; j < 8; ++j) v[j] = sStateD[rLN][sL + 16 * j];

            double sum = 0.0;
            #pragma unroll
            for (int j = 0; j < 8; ++j) sum += v[j];
            sum += __shfl_xor(sum, 1); sum += __shfl_xor(sum, 2);
            sum += __shfl_xor(sum, 4); sum += __shfl_xor(sum, 8);
            double mu = sum * (1.0 / 128.0);
            double sq = 0.0;
            #pragma unroll
            for (int j = 0; j < 8; ++j) { double dd = v[j] - mu; sq += dd * dd; }
            sq += __shfl_xor(sq, 1); sq += __shfl_xor(sq, 2);
            sq += __shfl_xor(sq, 4); sq += __shfl_xor(sq, 8);
            double rstd = 1.0 / sqrt(sq * (1.0 / 128.0) + 1e-5);

            #pragma unroll
            for (int j = 0; j < 8; ++j) {
                int c = sL + 16 * j;
                double inp = (double)sBi[c];
                #pragma unroll
                for (int k = 0; k < 8; ++k)
                    inp = fma(xv[k], (double)sWi[k][c], inp);
                double ln = (v[j] - mu) * rstd * (double)sGst[c] + (double)sBst[c];
                sStateD[rLN][c] = 0.618 * ln + 0.382 * inp;
            }
        }

        // ---------- step 2: 3 residual layers (all wave-local; W from L2) ----------
        for (int layer = 0; layer < NL; ++layer) {
            // LN reductions -> per-row rstd / mu*rstd in registers (wave broadcast)
            double rstdv[4], mu2v[4];
            {
                double v[8];
                #pragma unroll
                for (int j = 0; j < 8; ++j) v[j] = sStateD[rLN][sL + 16 * j];
                double sum = 0.0;
                #pragma unroll
                for (int j = 0; j < 8; ++j) sum += v[j];
                sum += __shfl_xor(sum, 1); sum += __shfl_xor(sum, 2);
                sum += __shfl_xor(sum, 4); sum += __shfl_xor(sum, 8);
                double mu = sum * (1.0 / 128.0);
                double sq = 0.0;
                #pragma unroll
                for (int j = 0; j < 8; ++j) { double dd = v[j] - mu; sq += dd * dd; }
                sq += __shfl_xor(sq, 1); sq += __shfl_xor(sq, 2);
                sq += __shfl_xor(sq, 4); sq += __shfl_xor(sq, 8);
                double rstd = 1.0 / sqrt(sq * (1.0 / 128.0) + 1e-5);
                double mu2  = mu * rstd;
                #pragma unroll
                for (int r = 0; r < 4; ++r) {
                    rstdv[r] = __shfl(rstd, r * 16);   // row r0+r lives at lanes 16r..16r+15
                    mu2v[r]  = __shfl(mu2,  r * 16);
                }
            }

            // GEMM: 4 rows x 2 adjacent cols per thread; W streamed from L2
            double acc[4][2];
            #pragma unroll
            for (int r = 0; r < 4; ++r) { acc[r][0] = 0.0; acc[r][1] = 0.0; }

            const double* gvec = sGsD[layer];
            const float*  wl   = Ws + (size_t)layer * D * D + c0;
            #pragma unroll 8
            for (int k0 = 0; k0 < D; k0 += 2) {
                float2 wA = *(const float2*)&wl[k0 * D];
                float2 wB = *(const float2*)&wl[(k0 + 1) * D];
                double2 gv = *(const double2*)&gvec[k0];
                double b00 = gv.x * (double)wA.x, b01 = gv.x * (double)wA.y;
                double b10 = gv.y * (double)wB.x, b11 = gv.y * (double)wB.y;
                #pragma unroll
                for (int r = 0; r < 4; ++r) {
                    double2 a = *(const double2*)&sStateD[r0 + r][k0];  // wave-uniform broadcast
                    acc[r][0] = fma(a.y, b10, fma(a.x, b00, acc[r][0]));
                    acc[r][1] = fma(a.y, b11, fma(a.x, b01, acc[r][1]));
                }
            }

            // epilogue: wave-local state RMW (no barrier)
            {
                double2 gwc = *(const double2*)&sGW[layer][c0];
                double2 bwc = *(const double2*)&sBWbs[layer][c0];
                #pragma unroll
                for (int r = 0; r < 4; ++r) {
                    double y0 = fma(rstdv[r], acc[r][0], fma(-mu2v[r], gwc.x, bwc.x));
                    double y1 = fma(rstdv[r], acc[r][1], fma(-mu2v[r], gwc.y, bwc.y));
                    double2 old = *(const double2*)&sStateD[r0 + r][c0];
                    double2 nw;
                    nw.x = old.x + c19_act_d(y0);
                    nw.y = old.y + c19_act_d(y1);
                    *(double2*)&sStateD[r0 + r][c0] = nw;
                }
            }
        }

        // ---------- step 3: out = state @ Wo + bo (wave-private rows) ----------
        {
            double accj[8];
            #pragma unroll
            for (int j = 0; j < 8; ++j) accj[j] = 0.0;
            #pragma unroll
            for (int u = 0; u < 8; ++u) {
                int k = sL + 16 * u;
                double s = sStateD[rLN][k];
                float4 w0 = *(const float4*)&sWo[k][0];
                float4 w1 = *(const float4*)&sWo[k][4];
                accj[0] = fma(s, (double)w0.x, accj[0]);
                accj[1] = fma(s, (double)w0.y, accj[1]);
                accj[2] = fma(s, (double)w0.z, accj[2]);
                accj[3] = fma(s, (double)w0.w, accj[3]);
                accj[4] = fma(s, (double)w1.x, accj[4]);
                accj[5] = fma(s, (double)w1.y, accj[5]);
                accj[6] = fma(s, (double)w1.z, accj[6]);
                accj[7] = fma(s, (double)w1.w, accj[7]);
            }
            #pragma unroll
            for (int j = 0; j < 8; ++j) {
                accj[j] += __shfl_xor(accj[j], 1);
                accj[j] += __shfl_xor(accj[j], 2);
                accj[j] += __shfl_xor(accj[j], 4);
                accj[j] += __shfl_xor(accj[j], 8);
            }
            // register-only select of accj[sL] (cndmask chain)
            double o = accj[0];
            #pragma unroll
            for (int j = 1; j < 8; ++j) o = (sL == j) ? accj[j] : o;
            if (sL < NB)
                out[((rowg + (size_t)rLN) * TT + (size_t)t) * NB + sL] =
                    (float)(o + (double)sBo[sL]);
        }
    }
}

extern "C" void kernel_launch(void* const* d_in, const int* in_sizes, int n_in,
                              void* d_out, int out_size, void* d_ws, size_t ws_size,
                              hipStream_t stream) {
    const float* x       = (const float*)d_in[0];
    const float* Wi      = (const float*)d_in[1];
    const float* bi      = (const float*)d_in[2];
    const float* Wo      = (const float*)d_in[3];
    const float* bo      = (const float*)d_in[4];
    const float* g_state = (const float*)d_in[5];
    const float* b_state = (const float*)d_in[6];
    const float* Ws      = (const float*)d_in[7];
    const float* bs      = (const float*)d_in[8];
    const float* gs      = (const float*)d_in[9];
    const float* betas   = (const float*)d_in[10];
    float* out = (float*)d_out;

    const int B = in_sizes[0] / (TT * NB);   // 65536
    dim3 grid(B / BR), block(BDIM);
    hipLaunchKernelGGL(miniphi_kernel, grid, block, 0, stream,
                       x, Wi, bi, Wo, bo, g_state, b_state, Ws, bs, gs, betas, out);
}

// Round 14
// 12636.459 us; speedup vs baseline: 1.9055x; 1.9055x over previous
//
#include <hip/hip_runtime.h>
#include <math.h>

#define BDIM 512
#define BR   32
#define D    128
#define TT   32
#define NB   8
#define NL   3
#define EBF  2048      // floats per "eighth" of a layer's W (16 k-rows x 128)
#define EBW  47104     // 23 * EBF : wrap point of the 24-eighth cycle

__device__ __forceinline__ double c19_act_d(double x) {
    const double PI_D = 3.14159265358979323846;
    const double L6   = 6.0 * PI_D;
    double scaled = x * (1.0 / PI_D);
    double n = floor(scaled);
    double t = scaled - n;
    double h = t * (1.0 - t);
    double halfn = n * 0.5;
    double fr = halfn - floor(halfn);   // 0.0 (even n) or 0.5 (odd n)
    double sgn = (fr < 0.25) ? 1.0 : -1.0;
    double core = PI_D * (sgn * h + 4.0 * h * h);
    double r = core;
    r = (x <= -L6) ? (x + L6) : r;
    r = (x >=  L6) ? (x - L6) : r;
    return r;
}

__global__ __launch_bounds__(BDIM) void miniphi_kernel(
    const float* __restrict__ x,  const float* __restrict__ Wi, const float* __restrict__ bi,
    const float* __restrict__ Wo, const float* __restrict__ bo,
    const float* __restrict__ g_state, const float* __restrict__ b_state,
    const float* __restrict__ Ws, const float* __restrict__ bs,
    const float* __restrict__ gs, const float* __restrict__ betas,
    float* __restrict__ out)
{
    __shared__ double sStateD[BR][D];   // 32768 B; rows wave-private (wave w: rows 4w..4w+3)
    __shared__ double sWp0[16 * D];     // 16384 B; W' ping buffer (f64, g-folded)
    __shared__ double sWp1[16 * D];     // 16384 B; W' pong buffer
    __shared__ float  sWi[NB][D];       //  4096 B
    __shared__ float  sWo[D][NB];       //  4096 B
    __shared__ double sGW[NL][D];       //  3072 B  (g @ W)[c]
    __shared__ double sBWbs[NL][D];     //  3072 B  (beta @ W)[c] + bs[c]
                                        //  total 79872 B = 78.0 KB -> 2 blocks/CU

    const int tid = threadIdx.x;

    for (int i = tid; i < NB * D; i += BDIM) sWi[i >> 7][i & 127] = Wi[i];
    for (int i = tid; i < D * NB; i += BDIM) sWo[i >> 3][i & 7] = Wo[i];
    for (int i = tid; i < BR * D; i += BDIM) sStateD[i >> 7][i & 127] = 0.0;
    if (tid < NL * D) {
        int ly = tid >> 7, c = tid & 127;
        const float* wl = Ws + (size_t)ly * D * D;
        double gw = 0.0, bw = 0.0;
        for (int k = 0; k < D; ++k) {
            double w = (double)wl[k * D + c];
            gw = fma((double)gs[ly * D + k], w, gw);
            bw = fma((double)betas[ly * D + k], w, bw);
        }
        sGW[ly][c] = gw;
        sBWbs[ly][c] = bw + (double)bs[ly * D + c];
    }
    __syncthreads();

    const int rLN = tid >> 4;          // 0..31 : LN row (wave w -> rows 4w..4w+3)
    const int sL  = tid & 15;          // 0..15 : lane owns cols {sL + 16*j}
    const int wv  = tid >> 6;          // wave 0..7
    const int ln_ = tid & 63;          // GEMM cols {ln_, ln_+64}
    const int r0  = wv * 4;            // GEMM rows (wave-private)
    const size_t rowg = (size_t)blockIdx.x * BR;

    const int ldoff = tid << 2;                          // float offset within an eighth
    const int wrb   = (tid >> 5) * D + (tid & 31) * 4;   // double offset in sWp
    const int gsub  = tid >> 5;                          // k-within-eighth for g lookup

    // ---- stage pipeline prologue: ldA=eighth0 -> buf0; ldB=eighth1 ----
    float4 ldA = *(const float4*)(Ws + 0 + ldoff);
    {
        double g = (double)gs[gsub];
        double* wb = sWp0 + wrb;
        double2 t0, t1;
        t0.x = g * (double)ldA.x; t0.y = g * (double)ldA.y;
        t1.x = g * (double)ldA.z; t1.y = g * (double)ldA.w;
        *(double2*)(wb)     = t0;
        *(double2*)(wb + 2) = t1;
    }
    float4 ldB = *(const float4*)(Ws + EBF + ldoff);
    __syncthreads();
    int doff = 2 * EBF;   // next LOAD  = eighth index j+2
    int woff = EBF;       // next WRITE = eighth index j+1

    double acc[4][2];
    double rstdv[4], mu2v[4];

// body for eighth e: WRITE buf[(e+1)&1] <- WLD ; LOAD -> FLD ; GEMM buf[e&1] ; BAR
#define STAGE_BODY(WLD, FLD, WBUF, RBUF, KB)                                    \
  { double g = (double)gs[(woff >> 7) + gsub];                                  \
    double* wb = (WBUF) + wrb;                                                  \
    double2 t0, t1;                                                             \
    t0.x = g * (double)(WLD).x; t0.y = g * (double)(WLD).y;                     \
    t1.x = g * (double)(WLD).z; t1.y = g * (double)(WLD).w;                     \
    *(double2*)(wb)     = t0;                                                   \
    *(double2*)(wb + 2) = t1;                                                   \
    woff = (woff == EBW) ? 0 : woff + EBF;                                      \
    (FLD) = *(const float4*)(Ws + doff + ldoff);                                \
    doff = (doff == EBW) ? 0 : doff + EBF;                                      \
    _Pragma("unroll")                                                           \
    for (int i = 0; i < 8; ++i) {                                               \
      const double* rb = (RBUF) + i * 2 * D;                                    \
      double b00 = rb[ln_],     b01 = rb[ln_ + 64];                             \
      double b10 = rb[D + ln_], b11 = rb[D + ln_ + 64];                         \
      _Pragma("unroll")                                                         \
      for (int r = 0; r < 4; ++r) {                                             \
        double2 a = *(const double2*)&sStateD[r0 + r][(KB) + 2 * i];            \
        acc[r][0] = fma(a.y, b10, fma(a.x, b00, acc[r][0]));                    \
        acc[r][1] = fma(a.y, b11, fma(a.x, b01, acc[r][1]));                    \
      }                                                                         \
    }                                                                           \
    __syncthreads(); }

    for (int t = 0; t < TT; ++t) {
        // ---------- step 1: state = 0.618*(LN(h)*g+b) + 0.382*(x_t @ Wi + bi) ----------
        {
            const float* xp = x + (rowg + (size_t)rLN) * (TT * NB) + (size_t)t * NB;
            float4 xa = *(const float4*)(xp);
            float4 xb = *(const float4*)(xp + 4);
            double xv[8] = {(double)xa.x, (double)xa.y, (double)xa.z, (double)xa.w,
                            (double)xb.x, (double)xb.y, (double)xb.z, (double)xb.w};

            double v[8];
            #pragma unroll
            for (int j = 0; j < 8; ++j) v[j] = sStateD[rLN][sL + 16 * j];

            double sum = 0.0;
            #pragma unroll
            for (int j = 0; j < 8; ++j) sum += v[j];
            sum += __shfl_xor(sum, 1); sum += __shfl_xor(sum, 2);
            sum += __shfl_xor(sum, 4); sum += __shfl_xor(sum, 8);
            double mu = sum * (1.0 / 128.0);
            double sq = 0.0;
            #pragma unroll
            for (int j = 0; j < 8; ++j) { double dd = v[j] - mu; sq += dd * dd; }
            sq += __shfl_xor(sq, 1); sq += __shfl_xor(sq, 2);
            sq += __shfl_xor(sq, 4); sq += __shfl_xor(sq, 8);
            double rstd = 1.0 / sqrt(sq * (1.0 / 128.0) + 1e-5);

            #pragma unroll
            for (int j = 0; j < 8; ++j) {
                int c = sL + 16 * j;
                double inp = (double)bi[c];
                #pragma unroll
                for (int k = 0; k < 8; ++k)
                    inp = fma(xv[k], (double)sWi[k][c], inp);
                double lnv = (v[j] - mu) * rstd * (double)g_state[c] + (double)b_state[c];
                sStateD[rLN][c] = 0.618 * lnv + 0.382 * inp;
            }
        }

        // ---------- step 2: 3 residual layers; GEMM on f64 W' ping-pong eighths ----------
        for (int ly = 0; ly < NL; ++ly) {
            // LN reductions (own rows) -> per-row rstd / mu*rstd in registers
            {
                double v[8];
                #pragma unroll
                for (int j = 0; j < 8; ++j) v[j] = sStateD[rLN][sL + 16 * j];
                double sum = 0.0;
                #pragma unroll
                for (int j = 0; j < 8; ++j) sum += v[j];
                sum += __shfl_xor(sum, 1); sum += __shfl_xor(sum, 2);
                sum += __shfl_xor(sum, 4); sum += __shfl_xor(sum, 8);
                double mu = sum * (1.0 / 128.0);
                double sq = 0.0;
                #pragma unroll
                for (int j = 0; j < 8; ++j) { double dd = v[j] - mu; sq += dd * dd; }
                sq += __shfl_xor(sq, 1); sq += __shfl_xor(sq, 2);
                sq += __shfl_xor(sq, 4); sq += __shfl_xor(sq, 8);
                double rstd = 1.0 / sqrt(sq * (1.0 / 128.0) + 1e-5);
                double mu2  = mu * rstd;
                #pragma unroll
                for (int r = 0; r < 4; ++r) {
                    rstdv[r] = __shfl(rstd, r * 16);
                    mu2v[r]  = __shfl(mu2,  r * 16);
                }
            }

            #pragma unroll
            for (int r = 0; r < 4; ++r) { acc[r][0] = 0.0; acc[r][1] = 0.0; }

            STAGE_BODY(ldB, ldA, sWp1, sWp0, 0)
            STAGE_BODY(ldA, ldB, sWp0, sWp1, 16)
            STAGE_BODY(ldB, ldA, sWp1, sWp0, 32)
            STAGE_BODY(ldA, ldB, sWp0, sWp1, 48)
            STAGE_BODY(ldB, ldA, sWp1, sWp0, 64)
            STAGE_BODY(ldA, ldB, sWp0, sWp1, 80)
            STAGE_BODY(ldB, ldA, sWp1, sWp0, 96)
            STAGE_BODY(ldA, ldB, sWp0, sWp1, 112)

            // epilogue: y = rstd*acc - (mu*rstd)*gW + (bW+bs); state += c19(y)  (own rows)
            {
                double gwc0 = sGW[ly][ln_],   gwc1 = sGW[ly][ln_ + 64];
                double bwc0 = sBWbs[ly][ln_], bwc1 = sBWbs[ly][ln_ + 64];
                #pragma unroll
                for (int r = 0; r < 4; ++r) {
                    double y0 = fma(rstdv[r], acc[r][0], fma(-mu2v[r], gwc0, bwc0));
                    double y1 = fma(rstdv[r], acc[r][1], fma(-mu2v[r], gwc1, bwc1));
                    sStateD[r0 + r][ln_]      += c19_act_d(y0);
                    sStateD[r0 + r][ln_ + 64] += c19_act_d(y1);
                }
            }
        }

        // ---------- step 3: out = state @ Wo + bo (own rows) ----------
        {
            double accj[8];
            #pragma unroll
            for (int j = 0; j < 8; ++j) accj[j] = 0.0;
            #pragma unroll
            for (int u = 0; u < 8; ++u) {
                int k = sL + 16 * u;
                double s = sStateD[rLN][k];
                float4 w0 = *(const float4*)&sWo[k][0];
                float4 w1 = *(const float4*)&sWo[k][4];
                accj[0] = fma(s, (double)w0.x, accj[0]);
                accj[1] = fma(s, (double)w0.y, accj[1]);
                accj[2] = fma(s, (double)w0.z, accj[2]);
                accj[3] = fma(s, (double)w0.w, accj[3]);
                accj[4] = fma(s, (double)w1.x, accj[4]);
                accj[5] = fma(s, (double)w1.y, accj[5]);
                accj[6] = fma(s, (double)w1.z, accj[6]);
                accj[7] = fma(s, (double)w1.w, accj[7]);
            }
            #pragma unroll
            for (int j = 0; j < 8; ++j) {
                accj[j] += __shfl_xor(accj[j], 1);
                accj[j] += __shfl_xor(accj[j], 2);
                accj[j] += __shfl_xor(accj[j], 4);
                accj[j] += __shfl_xor(accj[j], 8);
            }
            double o = accj[0];
            #pragma unroll
            for (int j = 1; j < 8; ++j) o = (sL == j) ? accj[j] : o;
            if (sL < NB)
                out[((rowg + (size_t)rLN) * TT + (size_t)t) * NB + sL] =
                    (float)(o + (double)bo[sL]);
        }
    }
#undef STAGE_BODY
}

extern "C" void kernel_launch(void* const* d_in, const int* in_sizes, int n_in,
                              void* d_out, int out_size, void* d_ws, size_t ws_size,
                              hipStream_t stream) {
    const float* x       = (const float*)d_in[0];
    const float* Wi      = (const float*)d_in[1];
    const float* bi      = (const float*)d_in[2];
    const float* Wo      = (const float*)d_in[3];
    const float* bo      = (const float*)d_in[4];
    const float* g_state = (const float*)d_in[5];
    const float* b_state = (const float*)d_in[6];
    const float* Ws      = (const float*)d_in[7];
    const float* bs      = (const float*)d_in[8];
    const float* gs      = (const float*)d_in[9];
    const float* betas   = (const float*)d_in[10];
    float* out = (float*)d_out;

    const int B = in_sizes[0] / (TT * NB);   // 65536
    dim3 grid(B / BR), block(BDIM);
    hipLaunchKernelGGL(miniphi_kernel, grid, block, 0, stream,
                       x, Wi, bi, Wo, bo, g_state, b_state, Ws, bs, gs, betas, out);
}

// Round 15
// 6551.624 us; speedup vs baseline: 3.6753x; 1.9288x over previous
//
#include <hip/hip_runtime.h>
#include <math.h>

#define BDIM 512
#define BR   32
#define D    128
#define SPD  130      // state LDS row stride (doubles)
#define WSP  130      // W' LDS row stride (doubles)
#define SWOP 12       // sWo row stride (floats)
#define TT   32
#define NB   8
#define NL   3

typedef double v4d __attribute__((ext_vector_type(4)));

__device__ __forceinline__ double c19_act_d(double x) {
    const double PI_D = 3.14159265358979323846;
    const double L6   = 6.0 * PI_D;
    double scaled = x * (1.0 / PI_D);
    double n = floor(scaled);
    double t = scaled - n;
    double h = t * (1.0 - t);
    double halfn = n * 0.5;
    double fr = halfn - floor(halfn);
    double sgn = (fr < 0.25) ? 1.0 : -1.0;
    double core = PI_D * (sgn * h + 4.0 * h * h);
    double r = core;
    r = (x <= -L6) ? (x + L6) : r;
    r = (x >=  L6) ? (x - L6) : r;
    return r;
}

__global__ __launch_bounds__(BDIM) void miniphi_kernel(
    const float* __restrict__ x,  const float* __restrict__ Wi, const float* __restrict__ bi,
    const float* __restrict__ Wo, const float* __restrict__ bo,
    const float* __restrict__ g_state, const float* __restrict__ b_state,
    const float* __restrict__ Ws, const float* __restrict__ bs,
    const float* __restrict__ gs, const float* __restrict__ betas,
    float* __restrict__ out)
{
    __shared__ double sState[BR][SPD];   // 33280 B
    __shared__ double sWp[64][WSP];      // 66560 B  f64 W' (g-folded) half-layer
    __shared__ float  sWi[NB][D];        //  4096 B
    __shared__ float  sWo[D][SWOP];      //  6144 B
    __shared__ float  sBi[D], sGst[D], sBst[D];
    __shared__ double sGsD[NL][D];       //  g (f64)
    __shared__ double sGW[NL][D];        //  (g @ W)[c]
    __shared__ double sBWbs[NL][D];      //  (beta @ W)[c] + bs[c]
    __shared__ double sRstd[BR], sMu2[BR];
    __shared__ float  sBo[NB];
    __shared__ int    sPR[64][4], sPC[64][4];
    __shared__ int    sFlag;             // total ~121 KB

    const int tid  = threadIdx.x;
    const int lane = tid & 63;
    const int wv   = tid >> 6;           // wave 0..7

    // ---- init tables ----
    for (int i = tid; i < NB * D; i += BDIM) sWi[i >> 7][i & 127] = Wi[i];
    for (int i = tid; i < D * NB; i += BDIM) sWo[i >> 3][i & 7] = Wo[i];
    for (int i = tid; i < D; i += BDIM) { sBi[i] = bi[i]; sGst[i] = g_state[i]; sBst[i] = b_state[i]; }
    for (int i = tid; i < NL * D; i += BDIM) sGsD[i >> 7][i & 127] = (double)gs[i];
    if (tid < NB) sBo[tid] = bo[tid];
    for (int i = tid; i < BR * D; i += BDIM) sState[i >> 7][i & 127] = 0.0;
    if (tid < NL * D) {
        int ly = tid >> 7, c = tid & 127;
        const float* wl = Ws + (size_t)ly * D * D;
        double gw = 0.0, bw = 0.0;
        for (int k = 0; k < D; ++k) {
            double w = (double)wl[k * D + c];
            gw = fma((double)gs[ly * D + k], w, gw);
            bw = fma((double)betas[ly * D + k], w, bw);
        }
        sGW[ly][c] = gw;
        sBWbs[ly][c] = bw + (double)bs[ly * D + c];
    }

    // ---- MFMA self-calibration probes (wave 0) ----
    if (wv == 0) {
        const int lm = lane & 15, lk = lane >> 4;
        v4d z = {0.0, 0.0, 0.0, 0.0};
        v4d p1 = __builtin_amdgcn_mfma_f64_16x16x4f64((double)lm, 1.0, z, 0, 0, 0);
        v4d p2 = __builtin_amdgcn_mfma_f64_16x16x4f64(1.0, (double)lm, z, 0, 0, 0);
        double pk = (double)(1 << lk);
        v4d p3 = __builtin_amdgcn_mfma_f64_16x16x4f64(pk, pk, z, 0, 0, 0);
        v4d p4 = __builtin_amdgcn_mfma_f64_16x16x4f64(1.0 + 0x1p-30, 1.0, z, 0, 0, 0);
        double pa5 = (lk == 0) ? 1.0 : 0x1p-52;
        v4d p5 = __builtin_amdgcn_mfma_f64_16x16x4f64(pa5, 1.0, z, 0, 0, 0);
        bool ok = true;
        #pragma unroll
        for (int i = 0; i < 4; ++i) {
            double v = p1[i]; int r = (int)(v * 0.25 + 0.5);
            ok = ok && (v == 4.0 * (double)r) && (r >= 0) && (r < 16);
            sPR[lane][i] = r;
            double w = p2[i]; int c2 = (int)(w * 0.25 + 0.5);
            ok = ok && (w == 4.0 * (double)c2) && (c2 >= 0) && (c2 < 16);
            sPC[lane][i] = c2;
            ok = ok && (p3[i] == 85.0);
            ok = ok && (p4[i] == 4.0 + 0x1p-28);
            ok = ok && (p5[i] == 1.0 + 3.0 * 0x1p-52);
        }
        unsigned long long bal = __ballot(ok ? 1 : 0);
        if (lane == 0) sFlag = (bal == 0xFFFFFFFFFFFFFFFFull) ? 1 : 0;
    }
    __syncthreads();

    const int useMfma = sFlag;           // block-uniform
    int pr[4], pc[4];
    #pragma unroll
    for (int i = 0; i < 4; ++i) { pr[i] = sPR[lane][i]; pc[i] = sPC[lane][i]; }

    const int rLN = tid >> 4;            // 0..31 LN row (wave w -> rows 4w..4w+3)
    const int sL  = tid & 15;
    const int lm  = lane & 15, lk = lane >> 4;
    const int n0  = wv * 16;             // MFMA col tile
    const int r0v = wv * 4;              // VALU-path rows
    const size_t rowg = (size_t)blockIdx.x * BR;

    for (int t = 0; t < TT; ++t) {
        // ---------- step 1 (wave-private rows) ----------
        {
            const float* xp = x + (rowg + (size_t)rLN) * (TT * NB) + (size_t)t * NB;
            float4 xa = *(const float4*)(xp);
            float4 xb = *(const float4*)(xp + 4);
            double xv[8] = {(double)xa.x, (double)xa.y, (double)xa.z, (double)xa.w,
                            (double)xb.x, (double)xb.y, (double)xb.z, (double)xb.w};
            double v[8];
            #pragma unroll
            for (int j = 0; j < 8; ++j) v[j] = sState[rLN][sL + 16 * j];
            double sum = 0.0;
            #pragma unroll
            for (int j = 0; j < 8; ++j) sum += v[j];
            sum += __shfl_xor(sum, 1); sum += __shfl_xor(sum, 2);
            sum += __shfl_xor(sum, 4); sum += __shfl_xor(sum, 8);
            double mu = sum * (1.0 / 128.0);
            double sq = 0.0;
            #pragma unroll
            for (int j = 0; j < 8; ++j) { double dd = v[j] - mu; sq += dd * dd; }
            sq += __shfl_xor(sq, 1); sq += __shfl_xor(sq, 2);
            sq += __shfl_xor(sq, 4); sq += __shfl_xor(sq, 8);
            double rstd = 1.0 / sqrt(sq * (1.0 / 128.0) + 1e-5);
            #pragma unroll
            for (int j = 0; j < 8; ++j) {
                int c = sL + 16 * j;
                double inp = (double)sBi[c];
                #pragma unroll
                for (int k = 0; k < 8; ++k)
                    inp = fma(xv[k], (double)sWi[k][c], inp);
                double ln = (v[j] - mu) * rstd * (double)sGst[c] + (double)sBst[c];
                sState[rLN][c] = 0.618 * ln + 0.382 * inp;
            }
        }

        // ---------- step 2: 3 residual layers ----------
        for (int ly = 0; ly < NL; ++ly) {
            // LN reductions -> sRstd/sMu2
            {
                double v[8];
                #pragma unroll
                for (int j = 0; j < 8; ++j) v[j] = sState[rLN][sL + 16 * j];
                double sum = 0.0;
                #pragma unroll
                for (int j = 0; j < 8; ++j) sum += v[j];
                sum += __shfl_xor(sum, 1); sum += __shfl_xor(sum, 2);
                sum += __shfl_xor(sum, 4); sum += __shfl_xor(sum, 8);
                double mu = sum * (1.0 / 128.0);
                double sq = 0.0;
                #pragma unroll
                for (int j = 0; j < 8; ++j) { double dd = v[j] - mu; sq += dd * dd; }
                sq += __shfl_xor(sq, 1); sq += __shfl_xor(sq, 2);
                sq += __shfl_xor(sq, 4); sq += __shfl_xor(sq, 8);
                double rstd = 1.0 / sqrt(sq * (1.0 / 128.0) + 1e-5);
                if (sL == 0) { sRstd[rLN] = rstd; sMu2[rLN] = mu * rstd; }
            }

            v4d acc0 = {0.0, 0.0, 0.0, 0.0};
            v4d acc1 = {0.0, 0.0, 0.0, 0.0};
            double accv[4][2];
            #pragma unroll
            for (int r = 0; r < 4; ++r) { accv[r][0] = 0.0; accv[r][1] = 0.0; }

            #pragma unroll
            for (int h = 0; h < 2; ++h) {
                // stage half h: W'[k][c] = g[k]*W[k][c] (f64, exact fold)
                {
                    const float* wsrc = Ws + (size_t)ly * D * D + h * 8192;
                    const double* gsl = &sGsD[ly][h * 64];
                    int c = 2 * lane;
                    #pragma unroll
                    for (int e = 0; e < 8; ++e) {
                        int kl = e * 8 + wv;
                        float2 w = *(const float2*)(wsrc + kl * D + c);
                        double g = gsl[kl];
                        double2 o; o.x = g * (double)w.x; o.y = g * (double)w.y;
                        *(double2*)&sWp[kl][c] = o;
                    }
                }
                __syncthreads();   // W' half visible (+ sRstd at h=0)

                if (useMfma) {
                    #pragma unroll
                    for (int k0 = 0; k0 < 64; k0 += 4) {
                        double b  = sWp[k0 + lk][n0 + lm];
                        double a0 = sState[lm][h * 64 + k0 + lk];
                        double a1 = sState[lm + 16][h * 64 + k0 + lk];
                        acc0 = __builtin_amdgcn_mfma_f64_16x16x4f64(a0, b, acc0, 0, 0, 0);
                        acc1 = __builtin_amdgcn_mfma_f64_16x16x4f64(a1, b, acc1, 0, 0, 0);
                    }
                } else {
                    #pragma unroll 8
                    for (int kk = 0; kk < 64; kk += 2) {
                        int kg = h * 64 + kk;
                        double b00 = sWp[kk][lane],     b01 = sWp[kk][lane + 64];
                        double b10 = sWp[kk + 1][lane], b11 = sWp[kk + 1][lane + 64];
                        #pragma unroll
                        for (int r = 0; r < 4; ++r) {
                            double2 a = *(const double2*)&sState[r0v + r][kg];
                            accv[r][0] = fma(a.y, b10, fma(a.x, b00, accv[r][0]));
                            accv[r][1] = fma(a.y, b11, fma(a.x, b01, accv[r][1]));
                        }
                    }
                }
                __syncthreads();   // GEMM reads of sWp/state done
            }

            // epilogue (state writes) — GEMM reads all drained by last barrier
            if (useMfma) {
                #pragma unroll
                for (int i = 0; i < 4; ++i) {
                    int row = pr[i];
                    int col = n0 + pc[i];
                    double gwc = sGW[ly][col], bwc = sBWbs[ly][col];
                    double y0 = fma(sRstd[row], acc0[i], fma(-sMu2[row], gwc, bwc));
                    double y1 = fma(sRstd[row + 16], acc1[i], fma(-sMu2[row + 16], gwc, bwc));
                    sState[row][col]      += c19_act_d(y0);
                    sState[row + 16][col] += c19_act_d(y1);
                }
            } else {
                double gwc0 = sGW[ly][lane],   gwc1 = sGW[ly][lane + 64];
                double bwc0 = sBWbs[ly][lane], bwc1 = sBWbs[ly][lane + 64];
                #pragma unroll
                for (int r = 0; r < 4; ++r) {
                    double rs = sRstd[r0v + r], m2 = sMu2[r0v + r];
                    double y0 = fma(rs, accv[r][0], fma(-m2, gwc0, bwc0));
                    double y1 = fma(rs, accv[r][1], fma(-m2, gwc1, bwc1));
                    sState[r0v + r][lane]      += c19_act_d(y0);
                    sState[r0v + r][lane + 64] += c19_act_d(y1);
                }
            }
            __syncthreads();   // state updated -> next LN/step3
        }

        // ---------- step 3: out = state @ Wo + bo (wave-private rows) ----------
        {
            double accj[8];
            #pragma unroll
            for (int j = 0; j < 8; ++j) accj[j] = 0.0;
            #pragma unroll
            for (int u = 0; u < 8; ++u) {
                int k = sL + 16 * u;
                double s = sState[rLN][k];
                float4 w0 = *(const float4*)&sWo[k][0];
                float4 w1 = *(const float4*)&sWo[k][4];
                accj[0] = fma(s, (double)w0.x, accj[0]);
                accj[1] = fma(s, (double)w0.y, accj[1]);
                accj[2] = fma(s, (double)w0.z, accj[2]);
                accj[3] = fma(s, (double)w0.w, accj[3]);
                accj[4] = fma(s, (double)w1.x, accj[4]);
                accj[5] = fma(s, (double)w1.y, accj[5]);
                accj[6] = fma(s, (double)w1.z, accj[6]);
                accj[7] = fma(s, (double)w1.w, accj[7]);
            }
            #pragma unroll
            for (int j = 0; j < 8; ++j) {
                accj[j] += __shfl_xor(accj[j], 1);
                accj[j] += __shfl_xor(accj[j], 2);
                accj[j] += __shfl_xor(accj[j], 4);
                accj[j] += __shfl_xor(accj[j], 8);
            }
            double o = accj[0];
            #pragma unroll
            for (int j = 1; j < 8; ++j) o = (sL == j) ? accj[j] : o;
            if (sL < NB)
                out[((rowg + (size_t)rLN) * TT + (size_t)t) * NB + sL] =
                    (float)(o + (double)sBo[sL]);
        }
    }
}

extern "C" void kernel_launch(void* const* d_in, const int* in_sizes, int n_in,
                              void* d_out, int out_size, void* d_ws, size_t ws_size,
                              hipStream_t stream) {
    const float* x       = (const float*)d_in[0];
    const float* Wi      = (const float*)d_in[1];
    const float* bi      = (const float*)d_in[2];
    const float* Wo      = (const float*)d_in[3];
    const float* bo      = (const float*)d_in[4];
    const float* g_state = (const float*)d_in[5];
    const float* b_state = (const float*)d_in[6];
    const float* Ws      = (const float*)d_in[7];
    const float* bs      = (const float*)d_in[8];
    const float* gs      = (const float*)d_in[9];
    const float* betas   = (const float*)d_in[10];
    float* out = (float*)d_out;

    const int B = in_sizes[0] / (TT * NB);   // 65536
    dim3 grid(B / BR), block(BDIM);
    hipLaunchKernelGGL(miniphi_kernel, grid, block, 0, stream,
                       x, Wi, bi, Wo, bo, g_state, b_state, Ws, bs, gs, betas, out);
}

// Round 16
// 5282.903 us; speedup vs baseline: 4.5579x; 1.2402x over previous
//
#include <hip/hip_runtime.h>
#include <math.h>

#define BDIM 512
#define BR   64
#define D    128
#define SPD  130      // state LDS row stride (doubles)
#define WSP  130      // W' LDS row stride (doubles)
#define SWOP 12       // sWo row stride (floats)
#define TT   32
#define NB   8
#define NL   3

typedef double v4d __attribute__((ext_vector_type(4)));

__device__ __forceinline__ double c19_act_d(double x) {
    const double PI_D = 3.14159265358979323846;
    const double L6   = 6.0 * PI_D;
    double scaled = x * (1.0 / PI_D);
    double n = floor(scaled);
    double t = scaled - n;
    double h = t * (1.0 - t);
    double halfn = n * 0.5;
    double fr = halfn - floor(halfn);
    double sgn = (fr < 0.25) ? 1.0 : -1.0;
    double core = PI_D * (sgn * h + 4.0 * h * h);
    double r = core;
    r = (x <= -L6) ? (x + L6) : r;
    r = (x >=  L6) ? (x - L6) : r;
    return r;
}

// prep: W'[ly][k][c] = g[ly][k] * W[ly][k][c]  (f64, exact fold) into d_ws
__global__ void miniphi_prep(const float* __restrict__ Ws, const float* __restrict__ gs,
                             double* __restrict__ wp) {
    int idx = blockIdx.x * 256 + threadIdx.x;   // 0 .. 49151
    wp[idx] = (double)gs[idx >> 7] * (double)Ws[idx];
}

__global__ __launch_bounds__(BDIM) void miniphi_kernel(
    const float* __restrict__ x,  const float* __restrict__ Wi, const float* __restrict__ bi,
    const float* __restrict__ Wo, const float* __restrict__ bo,
    const float* __restrict__ g_state, const float* __restrict__ b_state,
    const float* __restrict__ Ws, const float* __restrict__ bs,
    const float* __restrict__ gs, const float* __restrict__ betas,
    const double* __restrict__ wp,   // f64 g-folded W' in ws (or nullptr)
    float* __restrict__ out)
{
    __shared__ double sState[BR][SPD];     // 66560 B
    __shared__ double sWq[2][32][WSP];     // 66560 B  W' quarter double-buffer
    __shared__ float  sWi[NB][D];          //  4096 B
    __shared__ float  sWo[D][SWOP];        //  6144 B
    __shared__ float  sBi[D], sGst[D], sBst[D];
    __shared__ double sGsD[NL][D];         //  fallback g (f64)
    __shared__ double sGW[NL][D];          //  (g @ W)[c]
    __shared__ double sBWbs[NL][D];        //  (beta @ W)[c] + bs[c]
    __shared__ double sRstd[BR], sMu2[BR];
    __shared__ float  sBo[NB];
    __shared__ int    sPR[64][4], sPC[64][4];
    __shared__ int    sFlag;               // total ~154 KB

    const int tid  = threadIdx.x;
    const int lane = tid & 63;
    const int wv   = tid >> 6;             // wave 0..7

    for (int i = tid; i < NB * D; i += BDIM) sWi[i >> 7][i & 127] = Wi[i];
    for (int i = tid; i < D * NB; i += BDIM) sWo[i >> 3][i & 7] = Wo[i];
    for (int i = tid; i < D; i += BDIM) { sBi[i] = bi[i]; sGst[i] = g_state[i]; sBst[i] = b_state[i]; }
    for (int i = tid; i < NL * D; i += BDIM) sGsD[i >> 7][i & 127] = (double)gs[i];
    if (tid < NB) sBo[tid] = bo[tid];
    for (int i = tid; i < BR * D; i += BDIM) sState[i >> 7][i & 127] = 0.0;
    if (tid < NL * D) {
        int ly = tid >> 7, c = tid & 127;
        const float* wl = Ws + (size_t)ly * D * D;
        double gw = 0.0, bw = 0.0;
        for (int k = 0; k < D; ++k) {
            double w = (double)wl[k * D + c];
            gw = fma((double)gs[ly * D + k], w, gw);
            bw = fma((double)betas[ly * D + k], w, bw);
        }
        sGW[ly][c] = gw;
        sBWbs[ly][c] = bw + (double)bs[ly * D + c];
    }

    // ---- MFMA self-calibration probes (wave 0) ----
    if (wv == 0) {
        const int lm = lane & 15, lk = lane >> 4;
        v4d z = {0.0, 0.0, 0.0, 0.0};
        v4d p1 = __builtin_amdgcn_mfma_f64_16x16x4f64((double)lm, 1.0, z, 0, 0, 0);
        v4d p2 = __builtin_amdgcn_mfma_f64_16x16x4f64(1.0, (double)lm, z, 0, 0, 0);
        double pk = (double)(1 << lk);
        v4d p3 = __builtin_amdgcn_mfma_f64_16x16x4f64(pk, pk, z, 0, 0, 0);
        v4d p4 = __builtin_amdgcn_mfma_f64_16x16x4f64(1.0 + 0x1p-30, 1.0, z, 0, 0, 0);
        double pa5 = (lk == 0) ? 1.0 : 0x1p-52;
        v4d p5 = __builtin_amdgcn_mfma_f64_16x16x4f64(pa5, 1.0, z, 0, 0, 0);
        bool ok = true;
        #pragma unroll
        for (int i = 0; i < 4; ++i) {
            double v = p1[i]; int r = (int)(v * 0.25 + 0.5);
            ok = ok && (v == 4.0 * (double)r) && (r >= 0) && (r < 16);
            sPR[lane][i] = r;
            double w = p2[i]; int c2 = (int)(w * 0.25 + 0.5);
            ok = ok && (w == 4.0 * (double)c2) && (c2 >= 0) && (c2 < 16);
            sPC[lane][i] = c2;
            ok = ok && (p3[i] == 85.0);
            ok = ok && (p4[i] == 4.0 + 0x1p-28);
            ok = ok && (p5[i] == 1.0 + 3.0 * 0x1p-52);
        }
        unsigned long long bal = __ballot(ok ? 1 : 0);
        if (lane == 0) sFlag = (bal == 0xFFFFFFFFFFFFFFFFull) ? 1 : 0;
    }
    __syncthreads();

    const int useMfma = sFlag;
    int pr[4], pc[4];
    #pragma unroll
    for (int i = 0; i < 4; ++i) { pr[i] = sPR[lane][i]; pc[i] = sPC[lane][i]; }

    const int rLN = tid >> 3;              // 0..63 : LN row (wave w -> rows 8w..8w+7)
    const int sL  = tid & 7;               // lane owns cols {sL + 8*j, j=0..15}
    const int lm  = lane & 15, lk = lane >> 4;
    const int n0  = wv * 16;               // MFMA col tile
    const size_t rowg = (size_t)blockIdx.x * BR;

    // stage one 32-row quarter of W' into sWq[qb]; async when wp != nullptr
    #define STAGE_Q(LY, Q, QB)                                                      \
      { if (wp) {                                                                   \
          const double* src = wp + (((size_t)(LY) * D + (Q) * 32) * D);             \
          _Pragma("unroll")                                                         \
          for (int i_ = 0; i_ < 4; ++i_) {                                          \
              int kr_ = wv * 4 + i_;                                                \
              const double* g_ = src + (size_t)kr_ * D + lane * 2;                  \
              __builtin_amdgcn_global_load_lds(                                     \
                  (const __attribute__((address_space(1))) void*)g_,                \
                  (__attribute__((address_space(3))) void*)&sWq[QB][kr_][0],        \
                  16, 0, 0);                                                        \
          }                                                                         \
        } else {                                                                    \
          const float* src = Ws + (((size_t)(LY) * D + (Q) * 32) * D);              \
          const double* gl = &sGsD[LY][(Q) * 32];                                   \
          _Pragma("unroll")                                                         \
          for (int i_ = 0; i_ < 4; ++i_) {                                          \
              int kr_ = wv * 4 + i_;                                                \
              float2 w_ = *(const float2*)(src + (size_t)kr_ * D + lane * 2);       \
              double g_ = gl[kr_];                                                  \
              double2 o_; o_.x = g_ * (double)w_.x; o_.y = g_ * (double)w_.y;       \
              *(double2*)&sWq[QB][kr_][lane * 2] = o_;                              \
          }                                                                         \
        } }

    for (int t = 0; t < TT; ++t) {
        STAGE_Q(0, 0, 0)   // layer-0 q0; latency hides under step 1 + LN

        // ---------- step 1 (wave-private rows) ----------
        {
            const float* xp = x + (rowg + (size_t)rLN) * (TT * NB) + (size_t)t * NB;
            float4 xa = *(const float4*)(xp);
            float4 xb = *(const float4*)(xp + 4);
            double xv[8] = {(double)xa.x, (double)xa.y, (double)xa.z, (double)xa.w,
                            (double)xb.x, (double)xb.y, (double)xb.z, (double)xb.w};
            double v[16];
            #pragma unroll
            for (int j = 0; j < 16; ++j) v[j] = sState[rLN][sL + 8 * j];
            double sum = 0.0;
            #pragma unroll
            for (int j = 0; j < 16; ++j) sum += v[j];
            sum += __shfl_xor(sum, 1); sum += __shfl_xor(sum, 2); sum += __shfl_xor(sum, 4);
            double mu = sum * (1.0 / 128.0);
            double sq = 0.0;
            #pragma unroll
            for (int j = 0; j < 16; ++j) { double dd = v[j] - mu; sq += dd * dd; }
            sq += __shfl_xor(sq, 1); sq += __shfl_xor(sq, 2); sq += __shfl_xor(sq, 4);
            double rstd = 1.0 / sqrt(sq * (1.0 / 128.0) + 1e-5);
            #pragma unroll
            for (int j = 0; j < 16; ++j) {
                int c = sL + 8 * j;
                double inp = (double)sBi[c];
                #pragma unroll
                for (int k = 0; k < 8; ++k)
                    inp = fma(xv[k], (double)sWi[k][c], inp);
                double ln = (v[j] - mu) * rstd * (double)sGst[c] + (double)sBst[c];
                sState[rLN][c] = 0.618 * ln + 0.382 * inp;
            }
        }

        // ---------- step 2: 3 residual layers ----------
        for (int ly = 0; ly < NL; ++ly) {
            // LN reductions (own rows) -> sRstd/sMu2 ; overlaps q0 DMA
            {
                double v[16];
                #pragma unroll
                for (int j = 0; j < 16; ++j) v[j] = sState[rLN][sL + 8 * j];
                double sum = 0.0;
                #pragma unroll
                for (int j = 0; j < 16; ++j) sum += v[j];
                sum += __shfl_xor(sum, 1); sum += __shfl_xor(sum, 2); sum += __shfl_xor(sum, 4);
                double mu = sum * (1.0 / 128.0);
                double sq = 0.0;
                #pragma unroll
                for (int j = 0; j < 16; ++j) { double dd = v[j] - mu; sq += dd * dd; }
                sq += __shfl_xor(sq, 1); sq += __shfl_xor(sq, 2); sq += __shfl_xor(sq, 4);
                double rstd = 1.0 / sqrt(sq * (1.0 / 128.0) + 1e-5);
                if (sL == 0) { sRstd[rLN] = rstd; sMu2[rLN] = mu * rstd; }
            }
            __syncthreads();   // q0 staged (vmcnt/lgkm drained) + sRstd visible

            v4d acc0 = {0,0,0,0}, acc1 = {0,0,0,0}, acc2 = {0,0,0,0}, acc3 = {0,0,0,0};
            double accv[4][2];
            #pragma unroll
            for (int r = 0; r < 4; ++r) { accv[r][0] = 0.0; accv[r][1] = 0.0; }

            #pragma unroll
            for (int q = 0; q < 4; ++q) {
                const int qb = q & 1, qk = q * 32;
                // prefetch next quarter (overlaps this quarter's MFMA)
                if (q < 3) { STAGE_Q(ly, q + 1, (q + 1) & 1) }

                if (useMfma) {
                    #pragma unroll
                    for (int k0 = 0; k0 < 32; k0 += 4) {
                        double b  = sWq[qb][k0 + lk][n0 + lm];
                        double a0 = sState[lm     ][qk + k0 + lk];
                        double a1 = sState[lm + 16][qk + k0 + lk];
                        double a2 = sState[lm + 32][qk + k0 + lk];
                        double a3 = sState[lm + 48][qk + k0 + lk];
                        acc0 = __builtin_amdgcn_mfma_f64_16x16x4f64(a0, b, acc0, 0, 0, 0);
                        acc1 = __builtin_amdgcn_mfma_f64_16x16x4f64(a1, b, acc1, 0, 0, 0);
                        acc2 = __builtin_amdgcn_mfma_f64_16x16x4f64(a2, b, acc2, 0, 0, 0);
                        acc3 = __builtin_amdgcn_mfma_f64_16x16x4f64(a3, b, acc3, 0, 0, 0);
                    }
                } else {
                    // VALU fallback: wave wv -> rows 8wv..8wv+7? keep 4-row x 2-col per thread
                    const int r0v = wv * 8;   // 8 rows per wave, 2 cols per lane
                    #pragma unroll 4
                    for (int kk = 0; kk < 32; kk += 2) {
                        int kg = qk + kk;
                        double b00 = sWq[qb][kk][lane],     b01 = sWq[qb][kk][lane + 64];
                        double b10 = sWq[qb][kk + 1][lane], b11 = sWq[qb][kk + 1][lane + 64];
                        #pragma unroll
                        for (int r = 0; r < 4; ++r) {
                            double2 a = *(const double2*)&sState[r0v + 2 * r + (lane >> 6)][kg];
                            accv[r][0] = fma(a.y, b10, fma(a.x, b00, accv[r][0]));
                            accv[r][1] = fma(a.y, b11, fma(a.x, b01, accv[r][1]));
                        }
                    }
                }
                __syncthreads();   // drains next-quarter DMA; this quarter's reads done
            }

            // epilogue: y = rstd*acc - (mu*rstd)*gW + (bW+bs); state += c19(y)
            if (useMfma) {
                #pragma unroll
                for (int i = 0; i < 4; ++i) {
                    int col = n0 + pc[i];
                    double gwc = sGW[ly][col], bwc = sBWbs[ly][col];
                    int R0 = pr[i];
                    double y0 = fma(sRstd[R0],      acc0[i], fma(-sMu2[R0],      gwc, bwc));
                    double y1 = fma(sRstd[R0 + 16], acc1[i], fma(-sMu2[R0 + 16], gwc, bwc));
                    double y2 = fma(sRstd[R0 + 32], acc2[i], fma(-sMu2[R0 + 32], gwc, bwc));
                    double y3 = fma(sRstd[R0 + 48], acc3[i], fma(-sMu2[R0 + 48], gwc, bwc));
                    sState[R0][col]      += c19_act_d(y0);
                    sState[R0 + 16][col] += c19_act_d(y1);
                    sState[R0 + 32][col] += c19_act_d(y2);
                    sState[R0 + 48][col] += c19_act_d(y3);
                }
            } else {
                const int r0v = wv * 8;
                double gwc0 = sGW[ly][lane],   gwc1 = sGW[ly][lane + 64];
                double bwc0 = sBWbs[ly][lane], bwc1 = sBWbs[ly][lane + 64];
                #pragma unroll
                for (int r = 0; r < 4; ++r) {
                    int R = r0v + 2 * r;
                    double rs = sRstd[R], m2 = sMu2[R];
                    double y0 = fma(rs, accv[r][0], fma(-m2, gwc0, bwc0));
                    double y1 = fma(rs, accv[r][1], fma(-m2, gwc1, bwc1));
                    sState[R][lane]      += c19_act_d(y0);
                    sState[R][lane + 64] += c19_act_d(y1);
                }
            }
            __syncthreads();   // state updated -> next LN / step3

            if (ly + 1 < NL) { STAGE_Q(ly + 1, 0, 0) }   // overlaps next LN
        }

        // ---------- step 3: out = state @ Wo + bo (own rows) ----------
        {
            double accj[8];
            #pragma unroll
            for (int j = 0; j < 8; ++j) accj[j] = 0.0;
            #pragma unroll
            for (int u = 0; u < 16; ++u) {
                int k = sL + 8 * u;
                double s = sState[rLN][k];
                float4 w0 = *(const float4*)&sWo[k][0];
                float4 w1 = *(const float4*)&sWo[k][4];
                accj[0] = fma(s, (double)w0.x, accj[0]);
                accj[1] = fma(s, (double)w0.y, accj[1]);
                accj[2] = fma(s, (double)w0.z, accj[2]);
                accj[3] = fma(s, (double)w0.w, accj[3]);
                accj[4] = fma(s, (double)w1.x, accj[4]);
                accj[5] = fma(s, (double)w1.y, accj[5]);
                accj[6] = fma(s, (double)w1.z, accj[6]);
                accj[7] = fma(s, (double)w1.w, accj[7]);
            }
            #pragma unroll
            for (int j = 0; j < 8; ++j) {
                accj[j] += __shfl_xor(accj[j], 1);
                accj[j] += __shfl_xor(accj[j], 2);
                accj[j] += __shfl_xor(accj[j], 4);
            }
            double o = accj[0];
            #pragma unroll
            for (int j = 1; j < 8; ++j) o = (sL == j) ? accj[j] : o;
            out[((rowg + (size_t)rLN) * TT + (size_t)t) * NB + sL] =
                (float)(o + (double)sBo[sL]);
        }
    }
    #undef STAGE_Q
}

extern "C" void kernel_launch(void* const* d_in, const int* in_sizes, int n_in,
                              void* d_out, int out_size, void* d_ws, size_t ws_size,
                              hipStream_t stream) {
    const float* x       = (const float*)d_in[0];
    const float* Wi      = (const float*)d_in[1];
    const float* bi      = (const float*)d_in[2];
    const float* Wo      = (const float*)d_in[3];
    const float* bo      = (const float*)d_in[4];
    const float* g_state = (const float*)d_in[5];
    const float* b_state = (const float*)d_in[6];
    const float* Ws      = (const float*)d_in[7];
    const float* bs      = (const float*)d_in[8];
    const float* gs      = (const float*)d_in[9];
    const float* betas   = (const float*)d_in[10];
    float* out = (float*)d_out;

    const size_t wp_bytes = (size_t)NL * D * D * sizeof(double);   // 393216
    double* wp = (ws_size >= wp_bytes) ? (double*)d_ws : nullptr;
    if (wp) {
        dim3 pgrid(NL * D * D / 256), pblock(256);
        hipLaunchKernelGGL(miniphi_prep, pgrid, pblock, 0, stream, Ws, gs, wp);
    }

    const int B = in_sizes[0] / (TT * NB);   // 65536
    dim3 grid(B / BR), block(BDIM);
    hipLaunchKernelGGL(miniphi_kernel, grid, block, 0, stream,
                       x, Wi, bi, Wo, bo, g_state, b_state, Ws, bs, gs, betas, wp, out);
}

// Round 17
// 5208.250 us; speedup vs baseline: 4.6232x; 1.0143x over previous
//
#include <hip/hip_runtime.h>
#include <math.h>

#define BDIM 512
#define BR   64
#define D    128
#define SPD  130      // state LDS row stride (doubles)
#define WSP  130      // W' LDS row stride (doubles)
#define SWOP 12       // sWo row stride (floats)
#define TT   32
#define NB   8
#define NL   3

typedef double v4d __attribute__((ext_vector_type(4)));

__device__ __forceinline__ double c19_act_d(double x) {
    const double PI_D = 3.14159265358979323846;
    const double L6   = 6.0 * PI_D;
    double scaled = x * (1.0 / PI_D);
    double n = floor(scaled);
    double t = scaled - n;
    double h = t * (1.0 - t);
    double halfn = n * 0.5;
    double fr = halfn - floor(halfn);
    double sgn = (fr < 0.25) ? 1.0 : -1.0;
    double core = PI_D * (sgn * h + 4.0 * h * h);
    double r = core;
    r = (x <= -L6) ? (x + L6) : r;
    r = (x >=  L6) ? (x - L6) : r;
    return r;
}

// prep: W'[ly][k][c] = g[ly][k] * W[ly][k][c]  (f64, exact fold) into d_ws
__global__ void miniphi_prep(const float* __restrict__ Ws, const float* __restrict__ gs,
                             double* __restrict__ wp) {
    int idx = blockIdx.x * 256 + threadIdx.x;   // 0 .. 49151
    wp[idx] = (double)gs[idx >> 7] * (double)Ws[idx];
}

__global__ __launch_bounds__(BDIM) void miniphi_kernel(
    const float* __restrict__ x,  const float* __restrict__ Wi, const float* __restrict__ bi,
    const float* __restrict__ Wo, const float* __restrict__ bo,
    const float* __restrict__ g_state, const float* __restrict__ b_state,
    const float* __restrict__ Ws, const float* __restrict__ bs,
    const float* __restrict__ gs, const float* __restrict__ betas,
    const double* __restrict__ wp,   // f64 g-folded W' in ws (or nullptr)
    float* __restrict__ out)
{
    __shared__ double sState[BR][SPD];     // 66560 B
    __shared__ double sWq[2][32][WSP];     // 66560 B  W' quarter double-buffer
    __shared__ float  sWi[NB][D];
    __shared__ float  sWo[D][SWOP];
    __shared__ float  sBi[D], sGst[D], sBst[D];
    __shared__ double sGsD[NL][D];         // fallback g (f64)
    __shared__ double sGW[NL][D];          // (g @ W)[c]
    __shared__ double sBWbs[NL][D];        // (beta @ W)[c] + bs[c]
    __shared__ double sRstd[BR], sMu2[BR];
    __shared__ float  sBo[NB];
    __shared__ int    sPR[64][4], sPC[64][4];
    __shared__ int    sFlag;

    const int tid  = threadIdx.x;
    const int lane = tid & 63;
    const int wv   = tid >> 6;             // wave 0..7

    for (int i = tid; i < NB * D; i += BDIM) sWi[i >> 7][i & 127] = Wi[i];
    for (int i = tid; i < D * NB; i += BDIM) sWo[i >> 3][i & 7] = Wo[i];
    for (int i = tid; i < D; i += BDIM) { sBi[i] = bi[i]; sGst[i] = g_state[i]; sBst[i] = b_state[i]; }
    for (int i = tid; i < NL * D; i += BDIM) sGsD[i >> 7][i & 127] = (double)gs[i];
    if (tid < NB) sBo[tid] = bo[tid];
    for (int i = tid; i < BR * D; i += BDIM) sState[i >> 7][i & 127] = 0.0;
    if (tid < NL * D) {
        int ly = tid >> 7, c = tid & 127;
        const float* wl = Ws + (size_t)ly * D * D;
        double gw = 0.0, bw = 0.0;
        for (int k = 0; k < D; ++k) {
            double w = (double)wl[k * D + c];
            gw = fma((double)gs[ly * D + k], w, gw);
            bw = fma((double)betas[ly * D + k], w, bw);
        }
        sGW[ly][c] = gw;
        sBWbs[ly][c] = bw + (double)bs[ly * D + c];
    }

    // ---- MFMA self-calibration probes (wave 0) ----
    if (wv == 0) {
        const int lm = lane & 15, lk = lane >> 4;
        v4d z = {0.0, 0.0, 0.0, 0.0};
        v4d p1 = __builtin_amdgcn_mfma_f64_16x16x4f64((double)lm, 1.0, z, 0, 0, 0);
        v4d p2 = __builtin_amdgcn_mfma_f64_16x16x4f64(1.0, (double)lm, z, 0, 0, 0);
        double pk = (double)(1 << lk);
        v4d p3 = __builtin_amdgcn_mfma_f64_16x16x4f64(pk, pk, z, 0, 0, 0);
        v4d p4 = __builtin_amdgcn_mfma_f64_16x16x4f64(1.0 + 0x1p-30, 1.0, z, 0, 0, 0);
        double pa5 = (lk == 0) ? 1.0 : 0x1p-52;
        v4d p5 = __builtin_amdgcn_mfma_f64_16x16x4f64(pa5, 1.0, z, 0, 0, 0);
        bool ok = true;
        #pragma unroll
        for (int i = 0; i < 4; ++i) {
            double v = p1[i]; int r = (int)(v * 0.25 + 0.5);
            ok = ok && (v == 4.0 * (double)r) && (r >= 0) && (r < 16);
            sPR[lane][i] = r;
            double w = p2[i]; int c2 = (int)(w * 0.25 + 0.5);
            ok = ok && (w == 4.0 * (double)c2) && (c2 >= 0) && (c2 < 16);
            sPC[lane][i] = c2;
            ok = ok && (p3[i] == 85.0);
            ok = ok && (p4[i] == 4.0 + 0x1p-28);
            ok = ok && (p5[i] == 1.0 + 3.0 * 0x1p-52);
        }
        unsigned long long bal = __ballot(ok ? 1 : 0);
        if (lane == 0) sFlag = (bal == 0xFFFFFFFFFFFFFFFFull) ? 1 : 0;
    }
    __syncthreads();

    const int useMfma = sFlag;
    int pr[4], pc[4];
    #pragma unroll
    for (int i = 0; i < 4; ++i) { pr[i] = sPR[lane][i]; pc[i] = sPC[lane][i]; }

    const int rLN = tid >> 3;              // 0..63 : LN row (wave w -> rows 8w..8w+7)
    const int sL  = tid & 7;               // lane owns cols {sL + 8*j, j=0..15}
    const int lm  = lane & 15, lk = lane >> 4;
    const int n0  = wv * 16;               // MFMA col tile
    const int r0v = wv * 8;                // fallback rows
    const size_t rowg = (size_t)blockIdx.x * BR;

    #define STAGE_Q(LY, Q, QB)                                                      \
      { if (wp) {                                                                   \
          const double* src = wp + (((size_t)(LY) * D + (Q) * 32) * D);             \
          _Pragma("unroll")                                                         \
          for (int i_ = 0; i_ < 4; ++i_) {                                          \
              int kr_ = wv * 4 + i_;                                                \
              const double* g_ = src + (size_t)kr_ * D + lane * 2;                  \
              __builtin_amdgcn_global_load_lds(                                     \
                  (const __attribute__((address_space(1))) void*)g_,                \
                  (__attribute__((address_space(3))) void*)&sWq[QB][kr_][0],        \
                  16, 0, 0);                                                        \
          }                                                                         \
        } else {                                                                    \
          const float* src = Ws + (((size_t)(LY) * D + (Q) * 32) * D);              \
          const double* gl = &sGsD[LY][(Q) * 32];                                   \
          _Pragma("unroll")                                                         \
          for (int i_ = 0; i_ < 4; ++i_) {                                          \
              int kr_ = wv * 4 + i_;                                                \
              float2 w_ = *(const float2*)(src + (size_t)kr_ * D + lane * 2);       \
              double g_ = gl[kr_];                                                  \
              double2 o_; o_.x = g_ * (double)w_.x; o_.y = g_ * (double)w_.y;       \
              *(double2*)&sWq[QB][kr_][lane * 2] = o_;                              \
          }                                                                         \
        } }

    // MFMA quarter: reads sWq[QB], state k-range [QK, QK+32)
    #define GEMM_Q(QB, QK)                                                          \
      if (useMfma) {                                                                \
          _Pragma("unroll")                                                         \
          for (int k0 = 0; k0 < 32; k0 += 4) {                                      \
              double b  = sWq[QB][k0 + lk][n0 + lm];                                \
              double a0 = sState[lm     ][(QK) + k0 + lk];                          \
              double a1 = sState[lm + 16][(QK) + k0 + lk];                          \
              double a2 = sState[lm + 32][(QK) + k0 + lk];                          \
              double a3 = sState[lm + 48][(QK) + k0 + lk];                          \
              acc0 = __builtin_amdgcn_mfma_f64_16x16x4f64(a0, b, acc0, 0, 0, 0);    \
              acc1 = __builtin_amdgcn_mfma_f64_16x16x4f64(a1, b, acc1, 0, 0, 0);    \
              acc2 = __builtin_amdgcn_mfma_f64_16x16x4f64(a2, b, acc2, 0, 0, 0);    \
              acc3 = __builtin_amdgcn_mfma_f64_16x16x4f64(a3, b, acc3, 0, 0, 0);    \
          }                                                                         \
      } else {                                                                      \
          _Pragma("unroll 4")                                                       \
          for (int kk = 0; kk < 32; kk += 2) {                                      \
              int kg = (QK) + kk;                                                   \
              double b00 = sWq[QB][kk][lane],     b01 = sWq[QB][kk][lane + 64];     \
              double b10 = sWq[QB][kk + 1][lane], b11 = sWq[QB][kk + 1][lane + 64]; \
              _Pragma("unroll")                                                     \
              for (int r = 0; r < 8; ++r) {                                         \
                  double2 a = *(const double2*)&sState[r0v + r][kg];                \
                  accv[r][0] = fma(a.y, b10, fma(a.x, b00, accv[r][0]));            \
                  accv[r][1] = fma(a.y, b11, fma(a.x, b01, accv[r][1]));            \
              }                                                                     \
          }                                                                         \
      }

    STAGE_Q(0, 0, 0)   // prologue stage for t=0; drained at the post-step1 barrier

    for (int t = 0; t < TT; ++t) {
        // ---------- step 1 (wave-private rows) ----------
        {
            const float* xp = x + (rowg + (size_t)rLN) * (TT * NB) + (size_t)t * NB;
            float4 xa = *(const float4*)(xp);
            float4 xb = *(const float4*)(xp + 4);
            double xv[8] = {(double)xa.x, (double)xa.y, (double)xa.z, (double)xa.w,
                            (double)xb.x, (double)xb.y, (double)xb.z, (double)xb.w};
            double v[16];
            #pragma unroll
            for (int j = 0; j < 16; ++j) v[j] = sState[rLN][sL + 8 * j];
            double sum = 0.0;
            #pragma unroll
            for (int j = 0; j < 16; ++j) sum += v[j];
            sum += __shfl_xor(sum, 1); sum += __shfl_xor(sum, 2); sum += __shfl_xor(sum, 4);
            double mu = sum * (1.0 / 128.0);
            double sq = 0.0;
            #pragma unroll
            for (int j = 0; j < 16; ++j) { double dd = v[j] - mu; sq += dd * dd; }
            sq += __shfl_xor(sq, 1); sq += __shfl_xor(sq, 2); sq += __shfl_xor(sq, 4);
            double rstd = 1.0 / sqrt(sq * (1.0 / 128.0) + 1e-5);
            #pragma unroll
            for (int j = 0; j < 16; ++j) {
                int c = sL + 8 * j;
                double inp = (double)sBi[c];
                #pragma unroll
                for (int k = 0; k < 8; ++k)
                    inp = fma(xv[k], (double)sWi[k][c], inp);
                double ln = (v[j] - mu) * rstd * (double)sGst[c] + (double)sBst[c];
                sState[rLN][c] = 0.618 * ln + 0.382 * inp;
            }
        }
        __syncthreads();   // state ready; layer-0 q0 staged & drained

        // ---------- step 2: 3 residual layers; LN fused into q0's MFMA shadow ----------
        for (int ly = 0; ly < NL; ++ly) {
            v4d acc0 = {0,0,0,0}, acc1 = {0,0,0,0}, acc2 = {0,0,0,0}, acc3 = {0,0,0,0};
            double accv[8][2];
            #pragma unroll
            for (int r = 0; r < 8; ++r) { accv[r][0] = 0.0; accv[r][1] = 0.0; }

            // ---- q0 region: stage q1 | MFMA q0 | LN (streamed, low-reg) ----
            STAGE_Q(ly, 1, 1)
            GEMM_Q(0, 0)
            {
                double sum = 0.0;
                #pragma unroll
                for (int j = 0; j < 16; ++j) sum += sState[rLN][sL + 8 * j];
                sum += __shfl_xor(sum, 1); sum += __shfl_xor(sum, 2); sum += __shfl_xor(sum, 4);
                double mu = sum * (1.0 / 128.0);
                double sq = 0.0;
                #pragma unroll
                for (int j = 0; j < 16; ++j) { double dd = sState[rLN][sL + 8 * j] - mu; sq += dd * dd; }
                sq += __shfl_xor(sq, 1); sq += __shfl_xor(sq, 2); sq += __shfl_xor(sq, 4);
                double rstd = 1.0 / sqrt(sq * (1.0 / 128.0) + 1e-5);
                if (sL == 0) { sRstd[rLN] = rstd; sMu2[rLN] = mu * rstd; }
            }
            __syncthreads();

            // ---- q1 ----
            STAGE_Q(ly, 2, 0)
            GEMM_Q(1, 32)
            __syncthreads();

            // ---- q2 ----
            STAGE_Q(ly, 3, 1)
            GEMM_Q(0, 64)
            __syncthreads();

            // ---- q3: stage the NEXT layer's (or next t's) q0 ----
            if (ly + 1 < NL) { STAGE_Q(ly + 1, 0, 0) } else { STAGE_Q(0, 0, 0) }
            GEMM_Q(1, 96)
            __syncthreads();

            // ---- epilogue ----
            if (useMfma) {
                #pragma unroll
                for (int i = 0; i < 4; ++i) {
                    int col = n0 + pc[i];
                    double gwc = sGW[ly][col], bwc = sBWbs[ly][col];
                    int R0 = pr[i];
                    double y0 = fma(sRstd[R0],      acc0[i], fma(-sMu2[R0],      gwc, bwc));
                    double y1 = fma(sRstd[R0 + 16], acc1[i], fma(-sMu2[R0 + 16], gwc, bwc));
                    double y2 = fma(sRstd[R0 + 32], acc2[i], fma(-sMu2[R0 + 32], gwc, bwc));
                    double y3 = fma(sRstd[R0 + 48], acc3[i], fma(-sMu2[R0 + 48], gwc, bwc));
                    sState[R0][col]      += c19_act_d(y0);
                    sState[R0 + 16][col] += c19_act_d(y1);
                    sState[R0 + 32][col] += c19_act_d(y2);
                    sState[R0 + 48][col] += c19_act_d(y3);
                }
            } else {
                double gwc0 = sGW[ly][lane],   gwc1 = sGW[ly][lane + 64];
                double bwc0 = sBWbs[ly][lane], bwc1 = sBWbs[ly][lane + 64];
                #pragma unroll
                for (int r = 0; r < 8; ++r) {
                    int R = r0v + r;
                    double rs = sRstd[R], m2 = sMu2[R];
                    double y0 = fma(rs, accv[r][0], fma(-m2, gwc0, bwc0));
                    double y1 = fma(rs, accv[r][1], fma(-m2, gwc1, bwc1));
                    sState[R][lane]      += c19_act_d(y0);
                    sState[R][lane + 64] += c19_act_d(y1);
                }
            }
            __syncthreads();   // state final for next LN/GEMM/step3
        }

        // ---------- step 3: out = state @ Wo + bo (own rows) ----------
        {
            double accj[8];
            #pragma unroll
            for (int j = 0; j < 8; ++j) accj[j] = 0.0;
            #pragma unroll
            for (int u = 0; u < 16; ++u) {
                int k = sL + 8 * u;
                double s = sState[rLN][k];
                float4 w0 = *(const float4*)&sWo[k][0];
                float4 w1 = *(const float4*)&sWo[k][4];
                accj[0] = fma(s, (double)w0.x, accj[0]);
                accj[1] = fma(s, (double)w0.y, accj[1]);
                accj[2] = fma(s, (double)w0.z, accj[2]);
                accj[3] = fma(s, (double)w0.w, accj[3]);
                accj[4] = fma(s, (double)w1.x, accj[4]);
                accj[5] = fma(s, (double)w1.y, accj[5]);
                accj[6] = fma(s, (double)w1.z, accj[6]);
                accj[7] = fma(s, (double)w1.w, accj[7]);
            }
            #pragma unroll
            for (int j = 0; j < 8; ++j) {
                accj[j] += __shfl_xor(accj[j], 1);
                accj[j] += __shfl_xor(accj[j], 2);
                accj[j] += __shfl_xor(accj[j], 4);
            }
            double o = accj[0];
            #pragma unroll
            for (int j = 1; j < 8; ++j) o = (sL == j) ? accj[j] : o;
            out[((rowg + (size_t)rLN) * TT + (size_t)t) * NB + sL] =
                (float)(o + (double)sBo[sL]);
        }
    }
    #undef GEMM_Q
    #undef STAGE_Q
}

extern "C" void kernel_launch(void* const* d_in, const int* in_sizes, int n_in,
                              void* d_out, int out_size, void* d_ws, size_t ws_size,
                              hipStream_t stream) {
    const float* x       = (const float*)d_in[0];
    const float* Wi      = (const float*)d_in[1];
    const float* bi      = (const float*)d_in[2];
    const float* Wo      = (const float*)d_in[3];
    const float* bo      = (const float*)d_in[4];
    const float* g_state = (const float*)d_in[5];
    const float* b_state = (const float*)d_in[6];
    const float* Ws      = (const float*)d_in[7];
    const float* bs      = (const float*)d_in[8];
    const float* gs      = (const float*)d_in[9];
    const float* betas   = (const float*)d_in[10];
    float* out = (float*)d_out;

    const size_t wp_bytes = (size_t)NL * D * D * sizeof(double);   // 393216
    double* wp = (ws_size >= wp_bytes) ? (double*)d_ws : nullptr;
    if (wp) {
        dim3 pgrid(NL * D * D / 256), pblock(256);
        hipLaunchKernelGGL(miniphi_prep, pgrid, pblock, 0, stream, Ws, gs, wp);
    }

    const int B = in_sizes[0] / (TT * NB);   // 65536
    dim3 grid(B / BR), block(BDIM);
    hipLaunchKernelGGL(miniphi_kernel, grid, block, 0, stream,
                       x, Wi, bi, Wo, bo, g_state, b_state, Ws, bs, gs, betas, wp, out);
}

// Round 18
// 5146.355 us; speedup vs baseline: 4.6788x; 1.0120x over previous
//
#include <hip/hip_runtime.h>
#include <math.h>

#define BDIM 1024
#define BR   64
#define D    128
#define SPD  130      // state LDS row stride (doubles)
#define WSP  130      // W' LDS row stride (doubles)
#define SWOP 12       // sWo row stride (floats)
#define TT   32
#define NB   8
#define NL   3

typedef double v4d __attribute__((ext_vector_type(4)));

__device__ __forceinline__ double c19_act_d(double x) {
    const double PI_D = 3.14159265358979323846;
    const double L6   = 6.0 * PI_D;
    double scaled = x * (1.0 / PI_D);
    double n = floor(scaled);
    double t = scaled - n;
    double h = t * (1.0 - t);
    double halfn = n * 0.5;
    double fr = halfn - floor(halfn);
    double sgn = (fr < 0.25) ? 1.0 : -1.0;
    double core = PI_D * (sgn * h + 4.0 * h * h);
    double r = core;
    r = (x <= -L6) ? (x + L6) : r;
    r = (x >=  L6) ? (x - L6) : r;
    return r;
}

// prep: W'[ly][k][c] = g[ly][k] * W[ly][k][c]  (f64, exact fold) into d_ws
__global__ void miniphi_prep(const float* __restrict__ Ws, const float* __restrict__ gs,
                             double* __restrict__ wp) {
    int idx = blockIdx.x * 256 + threadIdx.x;   // 0 .. 49151
    wp[idx] = (double)gs[idx >> 7] * (double)Ws[idx];
}

__global__ __launch_bounds__(BDIM) void miniphi_kernel(
    const float* __restrict__ x,  const float* __restrict__ Wi, const float* __restrict__ bi,
    const float* __restrict__ Wo, const float* __restrict__ bo,
    const float* __restrict__ g_state, const float* __restrict__ b_state,
    const float* __restrict__ Ws, const float* __restrict__ bs,
    const float* __restrict__ gs, const float* __restrict__ betas,
    const double* __restrict__ wp,   // f64 g-folded W' in ws (or nullptr)
    float* __restrict__ out)
{
    __shared__ double sState[BR][SPD];     // 66560 B
    __shared__ double sWq[2][32][WSP];     // 66560 B  W' quarter double-buffer
    __shared__ float  sWi[NB][D];
    __shared__ float  sWo[D][SWOP];
    __shared__ float  sBi[D], sGst[D], sBst[D];
    __shared__ double sGsD[NL][D];         // fallback g (f64)
    __shared__ double sGW[NL][D];          // (g @ W)[c]
    __shared__ double sBWbs[NL][D];        // (beta @ W)[c] + bs[c]
    __shared__ double sRstd[BR], sMu2[BR];
    __shared__ float  sBo[NB];
    __shared__ int    sPR[64][4], sPC[64][4];
    __shared__ int    sFlag;               // ~157.3 KB

    const int tid  = threadIdx.x;
    const int lane = tid & 63;
    const int wv   = tid >> 6;             // wave 0..15

    for (int i = tid; i < NB * D; i += BDIM) sWi[i >> 7][i & 127] = Wi[i];
    for (int i = tid; i < D * NB; i += BDIM) sWo[i >> 3][i & 7] = Wo[i];
    for (int i = tid; i < D; i += BDIM) { sBi[i] = bi[i]; sGst[i] = g_state[i]; sBst[i] = b_state[i]; }
    for (int i = tid; i < NL * D; i += BDIM) sGsD[i >> 7][i & 127] = (double)gs[i];
    if (tid < NB) sBo[tid] = bo[tid];
    for (int i = tid; i < BR * D; i += BDIM) sState[i >> 7][i & 127] = 0.0;
    if (tid < NL * D) {
        int ly = tid >> 7, c = tid & 127;
        const float* wl = Ws + (size_t)ly * D * D;
        double gw = 0.0, bw = 0.0;
        for (int k = 0; k < D; ++k) {
            double w = (double)wl[k * D + c];
            gw = fma((double)gs[ly * D + k], w, gw);
            bw = fma((double)betas[ly * D + k], w, bw);
        }
        sGW[ly][c] = gw;
        sBWbs[ly][c] = bw + (double)bs[ly * D + c];
    }

    // ---- MFMA self-calibration probes (wave 0) ----
    if (wv == 0) {
        const int lm = lane & 15, lk = lane >> 4;
        v4d z = {0.0, 0.0, 0.0, 0.0};
        v4d p1 = __builtin_amdgcn_mfma_f64_16x16x4f64((double)lm, 1.0, z, 0, 0, 0);
        v4d p2 = __builtin_amdgcn_mfma_f64_16x16x4f64(1.0, (double)lm, z, 0, 0, 0);
        double pk = (double)(1 << lk);
        v4d p3 = __builtin_amdgcn_mfma_f64_16x16x4f64(pk, pk, z, 0, 0, 0);
        v4d p4 = __builtin_amdgcn_mfma_f64_16x16x4f64(1.0 + 0x1p-30, 1.0, z, 0, 0, 0);
        double pa5 = (lk == 0) ? 1.0 : 0x1p-52;
        v4d p5 = __builtin_amdgcn_mfma_f64_16x16x4f64(pa5, 1.0, z, 0, 0, 0);
        bool ok = true;
        #pragma unroll
        for (int i = 0; i < 4; ++i) {
            double v = p1[i]; int r = (int)(v * 0.25 + 0.5);
            ok = ok && (v == 4.0 * (double)r) && (r >= 0) && (r < 16);
            sPR[lane][i] = r;
            double w = p2[i]; int c2 = (int)(w * 0.25 + 0.5);
            ok = ok && (w == 4.0 * (double)c2) && (c2 >= 0) && (c2 < 16);
            sPC[lane][i] = c2;
            ok = ok && (p3[i] == 85.0);
            ok = ok && (p4[i] == 4.0 + 0x1p-28);
            ok = ok && (p5[i] == 1.0 + 3.0 * 0x1p-52);
        }
        unsigned long long bal = __ballot(ok ? 1 : 0);
        if (lane == 0) sFlag = (bal == 0xFFFFFFFFFFFFFFFFull) ? 1 : 0;
    }
    __syncthreads();

    const int useMfma = sFlag;
    int pr[4], pc[4];
    #pragma unroll
    for (int i = 0; i < 4; ++i) { pr[i] = sPR[lane][i]; pc[i] = sPC[lane][i]; }

    const int rLN = tid >> 4;              // 0..63 : LN row (16 lanes/row; wave w -> rows 4w..4w+3)
    const int sL  = tid & 15;              // lane owns cols {sL + 16*j, j=0..7}
    const int lm  = lane & 15, lk = lane >> 4;
    const int rp  = wv >> 3;               // row-pair group: rows rp*32 .. rp*32+31
    const int rb  = rp * 32;
    const int c0  = (wv & 7) * 16;         // MFMA col tile
    const int r0v = wv * 4;                // fallback rows (4/wave)
    const size_t rowg = (size_t)blockIdx.x * BR;

    #define STAGE_Q(LY, Q, QB)                                                      \
      { if (wp) {                                                                   \
          const double* src = wp + (((size_t)(LY) * D + (Q) * 32) * D);             \
          _Pragma("unroll")                                                         \
          for (int i_ = 0; i_ < 2; ++i_) {                                          \
              int kr_ = wv * 2 + i_;                                                \
              const double* g_ = src + (size_t)kr_ * D + lane * 2;                  \
              __builtin_amdgcn_global_load_lds(                                     \
                  (const __attribute__((address_space(1))) void*)g_,                \
                  (__attribute__((address_space(3))) void*)&sWq[QB][kr_][0],        \
                  16, 0, 0);                                                        \
          }                                                                         \
        } else {                                                                    \
          const float* src = Ws + (((size_t)(LY) * D + (Q) * 32) * D);              \
          const double* gl = &sGsD[LY][(Q) * 32];                                   \
          _Pragma("unroll")                                                         \
          for (int i_ = 0; i_ < 2; ++i_) {                                          \
              int kr_ = wv * 2 + i_;                                                \
              float2 w_ = *(const float2*)(src + (size_t)kr_ * D + lane * 2);       \
              double g_ = gl[kr_];                                                  \
              double2 o_; o_.x = g_ * (double)w_.x; o_.y = g_ * (double)w_.y;       \
              *(double2*)&sWq[QB][kr_][lane * 2] = o_;                              \
          }                                                                         \
        } }

    #define GEMM_Q(QB, QK)                                                          \
      if (useMfma) {                                                                \
          _Pragma("unroll")                                                         \
          for (int k0 = 0; k0 < 32; k0 += 4) {                                      \
              double b  = sWq[QB][k0 + lk][c0 + lm];                                \
              double a0 = sState[rb + lm     ][(QK) + k0 + lk];                     \
              double a1 = sState[rb + lm + 16][(QK) + k0 + lk];                     \
              acc0 = __builtin_amdgcn_mfma_f64_16x16x4f64(a0, b, acc0, 0, 0, 0);    \
              acc1 = __builtin_amdgcn_mfma_f64_16x16x4f64(a1, b, acc1, 0, 0, 0);    \
          }                                                                         \
      } else {                                                                      \
          _Pragma("unroll 4")                                                       \
          for (int kk = 0; kk < 32; kk += 2) {                                      \
              int kg = (QK) + kk;                                                   \
              double b00 = sWq[QB][kk][lane],     b01 = sWq[QB][kk][lane + 64];     \
              double b10 = sWq[QB][kk + 1][lane], b11 = sWq[QB][kk + 1][lane + 64]; \
              _Pragma("unroll")                                                     \
              for (int r = 0; r < 4; ++r) {                                         \
                  double2 a = *(const double2*)&sState[r0v + r][kg];                \
                  accv[r][0] = fma(a.y, b10, fma(a.x, b00, accv[r][0]));            \
                  accv[r][1] = fma(a.y, b11, fma(a.x, b01, accv[r][1]));            \
              }                                                                     \
          }                                                                         \
      }

    STAGE_Q(0, 0, 0)   // prologue stage for t=0; drained at the post-step1 barrier

    for (int t = 0; t < TT; ++t) {
        // ---------- step 1 (wave-private rows: wave w owns rows 4w..4w+3) ----------
        {
            const float* xp = x + (rowg + (size_t)rLN) * (TT * NB) + (size_t)t * NB;
            float4 xa = *(const float4*)(xp);
            float4 xb = *(const float4*)(xp + 4);
            double xv[8] = {(double)xa.x, (double)xa.y, (double)xa.z, (double)xa.w,
                            (double)xb.x, (double)xb.y, (double)xb.z, (double)xb.w};
            double v[8];
            #pragma unroll
            for (int j = 0; j < 8; ++j) v[j] = sState[rLN][sL + 16 * j];
            double sum = 0.0;
            #pragma unroll
            for (int j = 0; j < 8; ++j) sum += v[j];
            sum += __shfl_xor(sum, 1); sum += __shfl_xor(sum, 2);
            sum += __shfl_xor(sum, 4); sum += __shfl_xor(sum, 8);
            double mu = sum * (1.0 / 128.0);
            double sq = 0.0;
            #pragma unroll
            for (int j = 0; j < 8; ++j) { double dd = v[j] - mu; sq += dd * dd; }
            sq += __shfl_xor(sq, 1); sq += __shfl_xor(sq, 2);
            sq += __shfl_xor(sq, 4); sq += __shfl_xor(sq, 8);
            double rstd = 1.0 / sqrt(sq * (1.0 / 128.0) + 1e-5);
            #pragma unroll
            for (int j = 0; j < 8; ++j) {
                int c = sL + 16 * j;
                double inp = (double)sBi[c];
                #pragma unroll
                for (int k = 0; k < 8; ++k)
                    inp = fma(xv[k], (double)sWi[k][c], inp);
                double ln = (v[j] - mu) * rstd * (double)sGst[c] + (double)sBst[c];
                sState[rLN][c] = 0.618 * ln + 0.382 * inp;
            }
        }
        __syncthreads();   // state ready; layer-0 q0 staged & drained

        // ---------- step 2: 3 residual layers; LN fused into q0's MFMA shadow ----------
        for (int ly = 0; ly < NL; ++ly) {
            v4d acc0 = {0,0,0,0}, acc1 = {0,0,0,0};
            double accv[4][2];
            #pragma unroll
            for (int r = 0; r < 4; ++r) { accv[r][0] = 0.0; accv[r][1] = 0.0; }

            // ---- q0 region: stage q1 | MFMA q0 | LN (streamed) ----
            STAGE_Q(ly, 1, 1)
            GEMM_Q(0, 0)
            {
                double sum = 0.0;
                #pragma unroll
                for (int j = 0; j < 8; ++j) sum += sState[rLN][sL + 16 * j];
                sum += __shfl_xor(sum, 1); sum += __shfl_xor(sum, 2);
                sum += __shfl_xor(sum, 4); sum += __shfl_xor(sum, 8);
                double mu = sum * (1.0 / 128.0);
                double sq = 0.0;
                #pragma unroll
                for (int j = 0; j < 8; ++j) { double dd = sState[rLN][sL + 16 * j] - mu; sq += dd * dd; }
                sq += __shfl_xor(sq, 1); sq += __shfl_xor(sq, 2);
                sq += __shfl_xor(sq, 4); sq += __shfl_xor(sq, 8);
                double rstd = 1.0 / sqrt(sq * (1.0 / 128.0) + 1e-5);
                if (sL == 0) { sRstd[rLN] = rstd; sMu2[rLN] = mu * rstd; }
            }
            __syncthreads();

            // ---- q1 ----
            STAGE_Q(ly, 2, 0)
            GEMM_Q(1, 32)
            __syncthreads();

            // ---- q2 ----
            STAGE_Q(ly, 3, 1)
            GEMM_Q(0, 64)
            __syncthreads();

            // ---- q3: stage the NEXT layer's (or next t's) q0 ----
            if (ly + 1 < NL) { STAGE_Q(ly + 1, 0, 0) } else { STAGE_Q(0, 0, 0) }
            GEMM_Q(1, 96)
            __syncthreads();

            // ---- epilogue ----
            if (useMfma) {
                #pragma unroll
                for (int i = 0; i < 4; ++i) {
                    int col = c0 + pc[i];
                    double gwc = sGW[ly][col], bwc = sBWbs[ly][col];
                    int R0 = rb + pr[i];
                    double y0 = fma(sRstd[R0],      acc0[i], fma(-sMu2[R0],      gwc, bwc));
                    double y1 = fma(sRstd[R0 + 16], acc1[i], fma(-sMu2[R0 + 16], gwc, bwc));
                    sState[R0][col]      += c19_act_d(y0);
                    sState[R0 + 16][col] += c19_act_d(y1);
                }
            } else {
                double gwc0 = sGW[ly][lane],   gwc1 = sGW[ly][lane + 64];
                double bwc0 = sBWbs[ly][lane], bwc1 = sBWbs[ly][lane + 64];
                #pragma unroll
                for (int r = 0; r < 4; ++r) {
                    int R = r0v + r;
                    double rs = sRstd[R], m2 = sMu2[R];
                    double y0 = fma(rs, accv[r][0], fma(-m2, gwc0, bwc0));
                    double y1 = fma(rs, accv[r][1], fma(-m2, gwc1, bwc1));
                    sState[R][lane]      += c19_act_d(y0);
                    sState[R][lane + 64] += c19_act_d(y1);
                }
            }
            __syncthreads();   // state final for next LN/GEMM/step3
        }

        // ---------- step 3: out = state @ Wo + bo (own rows) ----------
        {
            double accj[8];
            #pragma unroll
            for (int j = 0; j < 8; ++j) accj[j] = 0.0;
            #pragma unroll
            for (int u = 0; u < 8; ++u) {
                int k = sL + 16 * u;
                double s = sState[rLN][k];
                float4 w0 = *(const float4*)&sWo[k][0];
                float4 w1 = *(const float4*)&sWo[k][4];
                accj[0] = fma(s, (double)w0.x, accj[0]);
                accj[1] = fma(s, (double)w0.y, accj[1]);
                accj[2] = fma(s, (double)w0.z, accj[2]);
                accj[3] = fma(s, (double)w0.w, accj[3]);
                accj[4] = fma(s, (double)w1.x, accj[4]);
                accj[5] = fma(s, (double)w1.y, accj[5]);
                accj[6] = fma(s, (double)w1.z, accj[6]);
                accj[7] = fma(s, (double)w1.w, accj[7]);
            }
            #pragma unroll
            for (int j = 0; j < 8; ++j) {
                accj[j] += __shfl_xor(accj[j], 1);
                accj[j] += __shfl_xor(accj[j], 2);
                accj[j] += __shfl_xor(accj[j], 4);
                accj[j] += __shfl_xor(accj[j], 8);
            }
            double o = accj[0];
            #pragma unroll
            for (int j = 1; j < 8; ++j) o = (sL == j) ? accj[j] : o;
            if (sL < NB)
                out[((rowg + (size_t)rLN) * TT + (size_t)t) * NB + sL] =
                    (float)(o + (double)sBo[sL]);
        }
    }
    #undef GEMM_Q
    #undef STAGE_Q
}

extern "C" void kernel_launch(void* const* d_in, const int* in_sizes, int n_in,
                              void* d_out, int out_size, void* d_ws, size_t ws_size,
                              hipStream_t stream) {
    const float* x       = (const float*)d_in[0];
    const float* Wi      = (const float*)d_in[1];
    const float* bi      = (const float*)d_in[2];
    const float* Wo      = (const float*)d_in[3];
    const float* bo      = (const float*)d_in[4];
    const float* g_state = (const float*)d_in[5];
    const float* b_state = (const float*)d_in[6];
    const float* Ws      = (const float*)d_in[7];
    const float* bs      = (const float*)d_in[8];
    const float* gs      = (const float*)d_in[9];
    const float* betas   = (const float*)d_in[10];
    float* out = (float*)d_out;

    const size_t wp_bytes = (size_t)NL * D * D * sizeof(double);   // 393216
    double* wp = (ws_size >= wp_bytes) ? (double*)d_ws : nullptr;
    if (wp) {
        dim3 pgrid(NL * D * D / 256), pblock(256);
        hipLaunchKernelGGL(miniphi_prep, pgrid, pblock, 0, stream, Ws, gs, wp);
    }

    const int B = in_sizes[0] / (TT * NB);   // 65536
    dim3 grid(B / BR), block(BDIM);
    hipLaunchKernelGGL(miniphi_kernel, grid, block, 0, stream,
                       x, Wi, bi, Wo, bo, g_state, b_state, Ws, bs, gs, betas, wp, out);
}